// Round 11
// baseline (229.914 us; speedup 1.0000x reference)
//
#include <hip/hip_runtime.h>
#include <math.h>

// GlobalAttention, single-streaming-pass version (v11 = v7 consolidated).
//   logits[b,h,n] = qW[h,:].LN(x[b,n,:])  (q folded through Wkv_k, LN folded via mu/rstd)
//   s[b,h,:]      = sum_n softmax(logits) * rstd_n * x[b,n,:]  (chunk partials, merged)
//   out           = cf + (Wkv_v @ (gamma*(S-UN)/E + beta)) @ proj_W.T + proj_b
// v11: reg-staging with stats-from-registers (v7), but 8-row tiles (wave owns
// rows 2wid,2wid+1) -> HALF the barriers; 128 rows/block, grid 512 = exactly
// 2 blocks/CU all-resident; part_s halved (16.7 MB) -> kmerge 2x faster.
// ONE lgkm-only barrier per tile; prefetch loads stay in flight across it.

#define BB 16
#define NN 4096
#define CC 1024
#define HH 8
#define DD 128
#define CHUNKS 32   // chunks per batch
#define RPB 128     // rows per block
#define TPT 8       // rows per tile
#define NT 16       // tiles per block

constexpr float EPS_ = 1e-5f;
constexpr float SCALE_ = 0.03125f; // 1024^-0.5

__device__ __forceinline__ float wsum(float v) {
#pragma unroll
  for (int o = 32; o; o >>= 1) v += __shfl_xor(v, o, 64);
  return v;
}

// DPP wave reduction: sum of all 64 lanes lands in lane 63 (VALU pipe, no LDS).
__device__ __forceinline__ float dpp_sum63(float v) {
  int t;
  t = __builtin_amdgcn_update_dpp(0, __float_as_int(v), 0x111, 0xf, 0xf, true);  v += __int_as_float(t);
  t = __builtin_amdgcn_update_dpp(0, __float_as_int(v), 0x112, 0xf, 0xf, true);  v += __int_as_float(t);
  t = __builtin_amdgcn_update_dpp(0, __float_as_int(v), 0x114, 0xf, 0xf, true);  v += __int_as_float(t);
  t = __builtin_amdgcn_update_dpp(0, __float_as_int(v), 0x118, 0xf, 0xf, true);  v += __int_as_float(t);
  t = __builtin_amdgcn_update_dpp(0, __float_as_int(v), 0x142, 0xa, 0xf, false); v += __int_as_float(t);
  t = __builtin_amdgcn_update_dpp(0, __float_as_int(v), 0x143, 0xc, 0xf, false); v += __int_as_float(t);
  return v;
}

// reduce + broadcast: total of 64 lanes as a wave-uniform value
__device__ __forceinline__ float rsum_u(float v) {
  return __int_as_float(__builtin_amdgcn_readlane(__float_as_int(dpp_sum63(v)), 63));
}

__device__ __forceinline__ float dot4(const float4& a, const float4& b) {
  return a.x * b.x + a.y * b.y + a.z * b.z + a.w * b.w;
}
__device__ __forceinline__ float sum4(const float4& a) {
  return (a.x + a.y) + (a.z + a.w);
}
__device__ __forceinline__ void fma4(float4& a, float s, const float4& v) {
  a.x += s * v.x; a.y += s * v.y; a.z += s * v.z; a.w += s * v.w;
}

// barrier that waits LDS ops only (keeps global prefetch loads in flight)
__device__ __forceinline__ void bar_lgkm() {
  asm volatile("s_waitcnt lgkmcnt(0)" ::: "memory");
  __builtin_amdgcn_sched_barrier(0);
  __builtin_amdgcn_s_barrier();
  __builtin_amdgcn_sched_barrier(0);
}

// ---- k0b: LN(class_feature) in-block, then qvec[j] = ln_cf . Wq[j,:] ----
__global__ __launch_bounds__(256) void k0b(const float* __restrict__ cf,
                                           const float* __restrict__ g,
                                           const float* __restrict__ be,
                                           const float* __restrict__ Wq,
                                           float* __restrict__ qvec) {
  __shared__ __align__(16) float lnbuf[CC];
  __shared__ float red[8];
  int t = threadIdx.x, lane = t & 63, wid = t >> 6;
  float x[4];
  float s = 0.f, s2 = 0.f;
#pragma unroll
  for (int j = 0; j < 4; ++j) {
    x[j] = cf[t * 4 + j];
    s += x[j];
    s2 += x[j] * x[j];
  }
  s = wsum(s);
  s2 = wsum(s2);
  if (lane == 0) { red[wid] = s; red[4 + wid] = s2; }
  __syncthreads();
  float S = red[0] + red[1] + red[2] + red[3];
  float S2 = red[4] + red[5] + red[6] + red[7];
  float mu = S * (1.f / CC);
  float rstd = rsqrtf(S2 * (1.f / CC) - mu * mu + EPS_);
#pragma unroll
  for (int j = 0; j < 4; ++j)
    lnbuf[t * 4 + j] = (x[j] - mu) * rstd * g[t * 4 + j] + be[t * 4 + j];
  __syncthreads();
  int j = blockIdx.x * 4 + wid;
  const float4* wr = (const float4*)(Wq + (size_t)j * CC);
  const float4* l4 = (const float4*)lnbuf;
  float a = 0.f;
#pragma unroll
  for (int k = 0; k < 4; ++k) a += dot4(wr[lane + 64 * k], l4[lane + 64 * k]);
  a = wsum(a);
  if (lane == 0) qvec[j] = a;
}

// ---- k0c: qW[h,c] = scale*sum_d qvec[h*D+d]*Wkv[h*D+d,c]; qWg = qW*gamma ----
__global__ __launch_bounds__(256) void k0c(const float* __restrict__ qvec,
                                           const float* __restrict__ Wkv,
                                           const float* __restrict__ kvg,
                                           float* __restrict__ qW,
                                           float* __restrict__ qWg) {
  int h = blockIdx.x >> 4;
  int c0 = (blockIdx.x & 15) * 64;
  int t = threadIdx.x, cl = t & 63, g = t >> 6;
  float a = 0.f;
#pragma unroll 8
  for (int d = g * 32; d < g * 32 + 32; ++d)
    a += qvec[h * DD + d] * Wkv[((size_t)(h * DD + d)) * CC + c0 + cl];
  __shared__ float red[4][64];
  red[g][cl] = a;
  __syncthreads();
  if (t < 64) {
    float v = (red[0][t] + red[1][t] + red[2][t] + red[3][t]) * SCALE_;
    qW[h * CC + c0 + t] = v;
    qWg[h * CC + c0 + t] = v * kvg[c0 + t];
  }
}

// ---- fused single pass over x (v11) ----
__global__ __launch_bounds__(256, 2) void kfused(
    const float* __restrict__ x, const float* __restrict__ qWg,
    const float* __restrict__ qW, const float* __restrict__ kvb,
    float* __restrict__ part_s, float* __restrict__ part_meu) {
  __shared__ __align__(16) float xbuf[2][TPT * CC];  // 2 x 32 KB
  __shared__ __align__(8) float mr_lds[2][TPT][2];   // {mu, rstd} double-buffered

  const int t = threadIdx.x, lane = t & 63, wid = t >> 6;
  const int chunk = blockIdx.x, b = blockIdx.y;
  const int bc = b * CHUNKS + chunk;
  const int h0 = wid * 2;
  const int ra = wid * 2, rb = ra + 1;  // this wave's two staged rows per tile

  const float* gx = x + ((size_t)b * NN + (size_t)chunk * RPB) * CC;

  // prefetch tile 0 into regs: pf[0..3] = row ra, pf[4..7] = row rb
  float4 pf[8];
  {
    const float4* g0 = (const float4*)gx;
#pragma unroll
    for (int k = 0; k < 4; ++k) {
      pf[k] = g0[ra * 256 + lane + 64 * k];
      pf[4 + k] = g0[rb * 256 + lane + 64 * k];
    }
  }

  // this wave's two heads' qWg fragments (live across the whole loop)
  float4 qw0[4], qw1[4];
  {
    const float4* a0 = (const float4*)(qWg + (size_t)h0 * CC);
    const float4* a1 = (const float4*)(qWg + (size_t)(h0 + 1) * CC);
#pragma unroll
    for (int k = 0; k < 4; ++k) {
      qw0[k] = a0[lane + 64 * k];
      qw1[k] = a1[lane + 64 * k];
    }
  }
  // qs = sum(qWg[h,:]); qb = qW[h,:].beta  (wave-uniform)
  float qs0, qs1, qb0, qb1;
  {
    float s0 = 0.f, s1 = 0.f, t0 = 0.f, t1 = 0.f;
    const float4* w0 = (const float4*)(qW + (size_t)h0 * CC);
    const float4* w1 = (const float4*)(qW + (size_t)(h0 + 1) * CC);
    const float4* b4 = (const float4*)kvb;
#pragma unroll
    for (int k = 0; k < 4; ++k) {
      s0 += sum4(qw0[k]);
      s1 += sum4(qw1[k]);
      float4 bt = b4[lane + 64 * k];
      t0 += dot4(w0[lane + 64 * k], bt);
      t1 += dot4(w1[lane + 64 * k], bt);
    }
    qs0 = rsum_u(s0);
    qs1 = rsum_u(s1);
    qb0 = rsum_u(t0);
    qb1 = rsum_u(t1);
  }

  float4 acc0[4], acc1[4];
#pragma unroll
  for (int k = 0; k < 4; ++k) {
    acc0[k] = make_float4(0.f, 0.f, 0.f, 0.f);
    acc1[k] = make_float4(0.f, 0.f, 0.f, 0.f);
  }
  float e0 = 0.f, e1 = 0.f, un0 = 0.f, un1 = 0.f;

  for (int tl = 0; tl < NT; ++tl) {
    const int cur = tl & 1;

    // ---- stats for rows ra, rb directly from the staging registers
    float lsA = 0.f, lsA2 = 0.f, lsB = 0.f, lsB2 = 0.f;
#pragma unroll
    for (int k = 0; k < 4; ++k) {
      lsA += sum4(pf[k]);
      lsA2 += dot4(pf[k], pf[k]);
      lsB += sum4(pf[4 + k]);
      lsB2 += dot4(pf[4 + k], pf[4 + k]);
    }
    // ---- write tile to LDS (same layout phase B reads)
    {
      float4* dst = (float4*)xbuf[cur];
#pragma unroll
      for (int k = 0; k < 4; ++k) {
        dst[ra * 256 + lane + 64 * k] = pf[k];
        dst[rb * 256 + lane + 64 * k] = pf[4 + k];
      }
    }
    // ---- reduce stats (4 independent chains); lane 63 publishes {mu, rstd}
    lsA = dpp_sum63(lsA);
    lsA2 = dpp_sum63(lsA2);
    lsB = dpp_sum63(lsB);
    lsB2 = dpp_sum63(lsB2);
    if (lane == 63) {
      float muA = lsA * (1.f / CC);
      float rsA = rsqrtf(lsA2 * (1.f / CC) - muA * muA + EPS_);
      float muB = lsB * (1.f / CC);
      float rsB = rsqrtf(lsB2 * (1.f / CC) - muB * muB + EPS_);
      mr_lds[cur][ra][0] = muA;
      mr_lds[cur][ra][1] = rsA;
      mr_lds[cur][rb][0] = muB;
      mr_lds[cur][rb][1] = rsB;
    }
    // ---- issue next tile's prefetch (regs free; lands during phase B)
    if (tl + 1 < NT) {
      const float4* gn = (const float4*)(gx + (size_t)(tl + 1) * (TPT * CC));
#pragma unroll
      for (int k = 0; k < 4; ++k) {
        pf[k] = gn[ra * 256 + lane + 64 * k];
        pf[4 + k] = gn[rb * 256 + lane + 64 * k];
      }
    }
    // ---- ONE barrier: ds_writes + mr visible; prefetch stays in flight
    bar_lgkm();

    // ---- phase B: branchless; this wave's 2 heads, all 8 rows
    const float4* xb4 = (const float4*)xbuf[cur];
#pragma unroll
    for (int r = 0; r < TPT; ++r) {
      float4 x0 = xb4[r * 256 + lane];
      float4 x1 = xb4[r * 256 + lane + 64];
      float4 x2 = xb4[r * 256 + lane + 128];
      float4 x3 = xb4[r * 256 + lane + 192];
      float a0 = dot4(qw0[0], x0), a1 = dot4(qw0[1], x1);
      float a2 = dot4(qw0[2], x2), a3 = dot4(qw0[3], x3);
      float c0 = dot4(qw1[0], x0), c1 = dot4(qw1[1], x1);
      float c2 = dot4(qw1[2], x2), c3 = dot4(qw1[3], x3);
      float D0 = rsum_u((a0 + a1) + (a2 + a3));
      float D1 = rsum_u((c0 + c1) + (c2 + c3));
      float2 mr = *(const float2*)mr_lds[cur][r];  // broadcast read
      float mu = mr.x, rs = mr.y;
      float l0 = fminf(rs * (D0 - mu * qs0) + qb0, 75.f);  // logits tiny; clamp = inf guard
      float l1 = fminf(rs * (D1 - mu * qs1) + qb1, 75.f);
      float p0 = __expf(l0), p1 = __expf(l1);
      float w0 = p0 * rs, w1 = p1 * rs;
      e0 += p0; e1 += p1;
      un0 += w0 * mu; un1 += w1 * mu;
      fma4(acc0[0], w0, x0); fma4(acc0[1], w0, x1);
      fma4(acc0[2], w0, x2); fma4(acc0[3], w0, x3);
      fma4(acc1[0], w1, x0); fma4(acc1[1], w1, x1);
      fma4(acc1[2], w1, x2); fma4(acc1[3], w1, x3);
    }
  }

  // ---- store partials (m == 0 by construction; logits bounded ~|2|)
  float4* p0 = (float4*)(part_s + ((size_t)bc * HH + h0) * CC);
  float4* p1 = (float4*)(part_s + ((size_t)bc * HH + h0 + 1) * CC);
#pragma unroll
  for (int k = 0; k < 4; ++k) {
    p0[64 * k + lane] = acc0[k];
    p1[64 * k + lane] = acc1[k];
  }
  if (lane == 0) {
    float* pm = part_meu + ((size_t)bc * HH + h0) * 2;
    pm[0] = e0; pm[1] = un0;
    pm[2] = e1; pm[3] = un1;
  }
}

// ---- merge partials: s[b,h,c] = gamma*(S-UN)/E + beta ----
__global__ __launch_bounds__(256) void kmerge(
    const float* __restrict__ part_s, const float* __restrict__ part_meu,
    const float* __restrict__ kvg, const float* __restrict__ kvb,
    float* __restrict__ s) {
  int h = blockIdx.x >> 2, q = blockIdx.x & 3, b = blockIdx.y;
  int col = q * 256 + threadIdx.x;
  float E = 0.f, UN = 0.f, a = 0.f;
  for (int ch = 0; ch < CHUNKS; ++ch) {
    const float* pm = part_meu + (((size_t)b * CHUNKS + ch) * HH + h) * 2;
    E += pm[0];
    UN += pm[1];
    a += part_s[(((size_t)b * CHUNKS + ch) * HH + h) * CC + col];
  }
  float inv = 1.f / E;
  s[((size_t)b * HH + h) * CC + col] = kvg[col] * (a - UN) * inv + kvb[col];
}

// ---- k5: agg[b,j] = Wkv[C+j,:] . s[b, j/D, :] ----
__global__ __launch_bounds__(256) void k5(const float* __restrict__ Wkv,
                                          const float* __restrict__ s,
                                          float* __restrict__ agg) {
  int lane = threadIdx.x & 63;
  int j = blockIdx.x * 4 + (threadIdx.x >> 6);
  int h = j >> 7;
  const float4* wr = (const float4*)(Wkv + ((size_t)(CC + j)) * CC);
  float4 wv[4];
#pragma unroll
  for (int k = 0; k < 4; ++k) wv[k] = wr[lane + 64 * k];
  for (int b = 0; b < BB; ++b) {
    const float4* s4 = (const float4*)(s + ((size_t)(b * HH + h)) * CC);
    float a = 0.f;
#pragma unroll
    for (int k = 0; k < 4; ++k) a += dot4(wv[k], s4[lane + 64 * k]);
    a = wsum(a);
    if (lane == 0) agg[b * CC + j] = a;
  }
}

// ---- k6: out[b,j] = cf[j] + agg[b,:] . proj_W[j,:] + proj_b[j] ----
__global__ __launch_bounds__(256) void k6(const float* __restrict__ pW,
                                          const float* __restrict__ agg,
                                          const float* __restrict__ cf,
                                          const float* __restrict__ pb,
                                          float* __restrict__ out) {
  int lane = threadIdx.x & 63;
  int j = blockIdx.x * 4 + (threadIdx.x >> 6);
  const float4* wr = (const float4*)(pW + (size_t)j * CC);
  float4 wv[4];
#pragma unroll
  for (int k = 0; k < 4; ++k) wv[k] = wr[lane + 64 * k];
  for (int b = 0; b < BB; ++b) {
    const float4* a4 = (const float4*)(agg + (size_t)b * CC);
    float a = 0.f;
#pragma unroll
    for (int k = 0; k < 4; ++k) a += dot4(wv[k], a4[lane + 64 * k]);
    a = wsum(a);
    if (lane == 0) out[b * CC + j] = cf[j] + a + pb[j];
  }
}

// ws float offsets
constexpr size_t WS_QVEC = 0;        // 1024
constexpr size_t WS_QW   = 1024;     // 8192
constexpr size_t WS_QWG  = 9216;     // 8192
constexpr size_t WS_S    = 17408;    // 131072
constexpr size_t WS_AGG  = 148480;   // 16384
constexpr size_t WS_PMEU = 164864;   // 8192
constexpr size_t WS_PART = 173056;   // 4194304 (16.8 MB)

extern "C" void kernel_launch(void* const* d_in, const int* in_sizes, int n_in,
                              void* d_out, int out_size, void* d_ws, size_t ws_size,
                              hipStream_t stream) {
  const float* cf = (const float*)d_in[0];
  const float* x = (const float*)d_in[1];
  const float* qg = (const float*)d_in[2];
  const float* qb = (const float*)d_in[3];
  const float* Wq = (const float*)d_in[4];
  const float* kvg = (const float*)d_in[5];
  const float* kvb = (const float*)d_in[6];
  const float* Wkv = (const float*)d_in[7];
  const float* pW = (const float*)d_in[8];
  const float* pb = (const float*)d_in[9];
  float* ws = (float*)d_ws;
  float* out = (float*)d_out;

  k0b<<<256, 256, 0, stream>>>(cf, qg, qb, Wq, ws + WS_QVEC);
  k0c<<<128, 256, 0, stream>>>(ws + WS_QVEC, Wkv, kvg, ws + WS_QW, ws + WS_QWG);
  kfused<<<dim3(CHUNKS, BB), 256, 0, stream>>>(x, ws + WS_QWG, ws + WS_QW, kvb,
                                               ws + WS_PART, ws + WS_PMEU);
  kmerge<<<dim3(HH * 4, BB), 256, 0, stream>>>(ws + WS_PART, ws + WS_PMEU, kvg, kvb,
                                               ws + WS_S);
  k5<<<256, 256, 0, stream>>>(Wkv, ws + WS_S, ws + WS_AGG);
  k6<<<256, 256, 0, stream>>>(pW, ws + WS_AGG, cf, pb, out);
}

// Round 12
// 102.117 us; speedup vs baseline: 2.2515x; 2.2515x over previous
//
#include <hip/hip_runtime.h>
#include <math.h>

// GlobalAttention, single-streaming-pass version (v12 = v7 + packed fp32).
//   logits[b,h,n] = qW[h,:].LN(x[b,n,:])  (q folded through Wkv_k, LN folded via mu/rstd)
//   s[b,h,:]      = sum_n softmax(logits) * rstd_n * x[b,n,:]  (chunk partials, merged)
//   out           = cf + (Wkv_v @ (gamma*(S-UN)/E + beta)) @ proj_W.T + proj_b
// v12: v7 schedule (reg-staged 4-row tiles, stats from staging regs, ONE
// lgkm-only barrier/tile) with v_pk_fma_f32/v_pk_add_f32 for the dot/acc/stat
// FMA groups (time scales ~1:1 with VALU issue count; pk halves the slots).
// Geometry: 128 rows/block, grid 512, partials 16.8 MB.

#define BB 16
#define NN 4096
#define CC 1024
#define HH 8
#define DD 128
#define CHUNKS 32   // chunks per batch
#define RPB 128     // rows per block
#define TPT 4       // rows per tile
#define NT 32       // tiles per block

constexpr float EPS_ = 1e-5f;
constexpr float SCALE_ = 0.03125f; // 1024^-0.5

typedef float v2f __attribute__((ext_vector_type(2)));

__device__ __forceinline__ void pkfma(v2f& d, v2f a, v2f b) {
  asm("v_pk_fma_f32 %0, %1, %2, %0" : "+v"(d) : "v"(a), "v"(b));
}
__device__ __forceinline__ void pkadd(v2f& d, v2f a) {
  asm("v_pk_add_f32 %0, %1, %0" : "+v"(d) : "v"(a));
}
__device__ __forceinline__ v2f lo2(const float4& f) { return v2f{f.x, f.y}; }
__device__ __forceinline__ v2f hi2(const float4& f) { return v2f{f.z, f.w}; }

__device__ __forceinline__ float wsum(float v) {
#pragma unroll
  for (int o = 32; o; o >>= 1) v += __shfl_xor(v, o, 64);
  return v;
}

// DPP wave reduction: sum of all 64 lanes lands in lane 63 (VALU pipe, no LDS).
__device__ __forceinline__ float dpp_sum63(float v) {
  int t;
  t = __builtin_amdgcn_update_dpp(0, __float_as_int(v), 0x111, 0xf, 0xf, true);  v += __int_as_float(t);
  t = __builtin_amdgcn_update_dpp(0, __float_as_int(v), 0x112, 0xf, 0xf, true);  v += __int_as_float(t);
  t = __builtin_amdgcn_update_dpp(0, __float_as_int(v), 0x114, 0xf, 0xf, true);  v += __int_as_float(t);
  t = __builtin_amdgcn_update_dpp(0, __float_as_int(v), 0x118, 0xf, 0xf, true);  v += __int_as_float(t);
  t = __builtin_amdgcn_update_dpp(0, __float_as_int(v), 0x142, 0xa, 0xf, false); v += __int_as_float(t);
  t = __builtin_amdgcn_update_dpp(0, __float_as_int(v), 0x143, 0xc, 0xf, false); v += __int_as_float(t);
  return v;
}

// reduce + broadcast: total of 64 lanes as a wave-uniform value
__device__ __forceinline__ float rsum_u(float v) {
  return __int_as_float(__builtin_amdgcn_readlane(__float_as_int(dpp_sum63(v)), 63));
}

__device__ __forceinline__ float dot4(const float4& a, const float4& b) {
  return a.x * b.x + a.y * b.y + a.z * b.z + a.w * b.w;
}
__device__ __forceinline__ float sum4(const float4& a) {
  return (a.x + a.y) + (a.z + a.w);
}

// barrier that waits LDS ops only (keeps global prefetch loads in flight)
__device__ __forceinline__ void bar_lgkm() {
  asm volatile("s_waitcnt lgkmcnt(0)" ::: "memory");
  __builtin_amdgcn_sched_barrier(0);
  __builtin_amdgcn_s_barrier();
  __builtin_amdgcn_sched_barrier(0);
}

// ---- k0b: LN(class_feature) in-block, then qvec[j] = ln_cf . Wq[j,:] ----
__global__ __launch_bounds__(256) void k0b(const float* __restrict__ cf,
                                           const float* __restrict__ g,
                                           const float* __restrict__ be,
                                           const float* __restrict__ Wq,
                                           float* __restrict__ qvec) {
  __shared__ __align__(16) float lnbuf[CC];
  __shared__ float red[8];
  int t = threadIdx.x, lane = t & 63, wid = t >> 6;
  float x[4];
  float s = 0.f, s2 = 0.f;
#pragma unroll
  for (int j = 0; j < 4; ++j) {
    x[j] = cf[t * 4 + j];
    s += x[j];
    s2 += x[j] * x[j];
  }
  s = wsum(s);
  s2 = wsum(s2);
  if (lane == 0) { red[wid] = s; red[4 + wid] = s2; }
  __syncthreads();
  float S = red[0] + red[1] + red[2] + red[3];
  float S2 = red[4] + red[5] + red[6] + red[7];
  float mu = S * (1.f / CC);
  float rstd = rsqrtf(S2 * (1.f / CC) - mu * mu + EPS_);
#pragma unroll
  for (int j = 0; j < 4; ++j)
    lnbuf[t * 4 + j] = (x[j] - mu) * rstd * g[t * 4 + j] + be[t * 4 + j];
  __syncthreads();
  int j = blockIdx.x * 4 + wid;
  const float4* wr = (const float4*)(Wq + (size_t)j * CC);
  const float4* l4 = (const float4*)lnbuf;
  float a = 0.f;
#pragma unroll
  for (int k = 0; k < 4; ++k) a += dot4(wr[lane + 64 * k], l4[lane + 64 * k]);
  a = wsum(a);
  if (lane == 0) qvec[j] = a;
}

// ---- k0c: qW[h,c] = scale*sum_d qvec[h*D+d]*Wkv[h*D+d,c]; qWg = qW*gamma ----
__global__ __launch_bounds__(256) void k0c(const float* __restrict__ qvec,
                                           const float* __restrict__ Wkv,
                                           const float* __restrict__ kvg,
                                           float* __restrict__ qW,
                                           float* __restrict__ qWg) {
  int h = blockIdx.x >> 4;
  int c0 = (blockIdx.x & 15) * 64;
  int t = threadIdx.x, cl = t & 63, g = t >> 6;
  float a = 0.f;
#pragma unroll 8
  for (int d = g * 32; d < g * 32 + 32; ++d)
    a += qvec[h * DD + d] * Wkv[((size_t)(h * DD + d)) * CC + c0 + cl];
  __shared__ float red[4][64];
  red[g][cl] = a;
  __syncthreads();
  if (t < 64) {
    float v = (red[0][t] + red[1][t] + red[2][t] + red[3][t]) * SCALE_;
    qW[h * CC + c0 + t] = v;
    qWg[h * CC + c0 + t] = v * kvg[c0 + t];
  }
}

// ---- fused single pass over x (v12) ----
__global__ __launch_bounds__(256, 2) void kfused(
    const float* __restrict__ x, const float* __restrict__ qWg,
    const float* __restrict__ qW, const float* __restrict__ kvb,
    float* __restrict__ part_s, float* __restrict__ part_meu) {
  __shared__ __align__(16) float xbuf[2][TPT * CC];  // 2 x 16 KB
  __shared__ __align__(8) float mr_lds[2][TPT][2];   // {mu, rstd}, double-buffered

  const int t = threadIdx.x, lane = t & 63, wid = t >> 6;
  const int chunk = blockIdx.x, b = blockIdx.y;
  const int bc = b * CHUNKS + chunk;
  const int h0 = wid * 2;

  const float* gx = x + ((size_t)b * NN + (size_t)chunk * RPB) * CC;
  // thread t's slice of a tile: row 'wid', float4 cols (lane + 64k), k=0..3
  const int sl = wid * 256 + lane;

  // prefetch tile 0 into regs (in flight during prologue math)
  float4 pf[4];
  {
    const float4* g0 = (const float4*)gx;
#pragma unroll
    for (int k = 0; k < 4; ++k) pf[k] = g0[sl + 64 * k];
  }

  // this wave's two heads' qWg fragments (live across the whole loop)
  float4 qw0[4], qw1[4];
  {
    const float4* a0 = (const float4*)(qWg + (size_t)h0 * CC);
    const float4* a1 = (const float4*)(qWg + (size_t)(h0 + 1) * CC);
#pragma unroll
    for (int k = 0; k < 4; ++k) {
      qw0[k] = a0[lane + 64 * k];
      qw1[k] = a1[lane + 64 * k];
    }
  }
  // qs = sum(qWg[h,:]); qb = qW[h,:].beta  (wave-uniform)
  float qs0, qs1, qb0, qb1;
  {
    float s0 = 0.f, s1 = 0.f, t0 = 0.f, t1 = 0.f;
    const float4* w0 = (const float4*)(qW + (size_t)h0 * CC);
    const float4* w1 = (const float4*)(qW + (size_t)(h0 + 1) * CC);
    const float4* b4 = (const float4*)kvb;
#pragma unroll
    for (int k = 0; k < 4; ++k) {
      s0 += sum4(qw0[k]);
      s1 += sum4(qw1[k]);
      float4 bt = b4[lane + 64 * k];
      t0 += dot4(w0[lane + 64 * k], bt);
      t1 += dot4(w1[lane + 64 * k], bt);
    }
    qs0 = rsum_u(s0);
    qs1 = rsum_u(s1);
    qb0 = rsum_u(t0);
    qb1 = rsum_u(t1);
  }

  // accumulators as v2f pairs (8 per head = 4 float4)
  v2f acc0[8], acc1[8];
#pragma unroll
  for (int k = 0; k < 8; ++k) {
    acc0[k] = v2f{0.f, 0.f};
    acc1[k] = v2f{0.f, 0.f};
  }
  float e0 = 0.f, e1 = 0.f, un0 = 0.f, un1 = 0.f;

  for (int tl = 0; tl < NT; ++tl) {
    const int cur = tl & 1;
    // ---- stats for row 'wid' directly from the staging registers (pk math)
    {
      v2f sv = v2f{0.f, 0.f}, sv2 = v2f{0.f, 0.f};
#pragma unroll
      for (int k = 0; k < 4; ++k) {
        v2f plo = lo2(pf[k]), phi = hi2(pf[k]);
        pkadd(sv, plo);
        pkadd(sv, phi);
        pkfma(sv2, plo, plo);
        pkfma(sv2, phi, phi);
      }
      float ls = sv.x + sv.y;
      float ls2 = sv2.x + sv2.y;
      // ---- write tile to LDS (same layout phase B reads)
      {
        float4* dst = (float4*)xbuf[cur];
#pragma unroll
        for (int k = 0; k < 4; ++k) dst[sl + 64 * k] = pf[k];
      }
      ls = dpp_sum63(ls);
      ls2 = dpp_sum63(ls2);
      if (lane == 63) {
        float mu = ls * (1.f / CC);
        float rs = rsqrtf(ls2 * (1.f / CC) - mu * mu + EPS_);
        mr_lds[cur][wid][0] = mu;
        mr_lds[cur][wid][1] = rs;
      }
    }
    // ---- issue next tile's prefetch (regs now free; lands during phase B)
    if (tl + 1 < NT) {
      const float4* gn = (const float4*)(gx + (size_t)(tl + 1) * (TPT * CC));
#pragma unroll
      for (int k = 0; k < 4; ++k) pf[k] = gn[sl + 64 * k];
    }
    // ---- one barrier: ds_writes + mr_lds visible; prefetch stays in flight
    bar_lgkm();

    // ---- phase B: branchless; this wave's 2 heads, all 4 rows (pk math)
    const float4* xb4 = (const float4*)xbuf[cur];
#pragma unroll
    for (int r = 0; r < TPT; ++r) {
      float4 x0 = xb4[r * 256 + lane];
      float4 x1 = xb4[r * 256 + lane + 64];
      float4 x2 = xb4[r * 256 + lane + 128];
      float4 x3 = xb4[r * 256 + lane + 192];
      v2f xl0 = lo2(x0), xh0 = hi2(x0), xl1 = lo2(x1), xh1 = hi2(x1);
      v2f xl2 = lo2(x2), xh2 = hi2(x2), xl3 = lo2(x3), xh3 = hi2(x3);
      // dots: 8 pk_fma per head (independent chains)
      v2f d0v = v2f{0.f, 0.f}, d1v = v2f{0.f, 0.f};
      pkfma(d0v, lo2(qw0[0]), xl0); pkfma(d0v, hi2(qw0[0]), xh0);
      pkfma(d0v, lo2(qw0[1]), xl1); pkfma(d0v, hi2(qw0[1]), xh1);
      pkfma(d0v, lo2(qw0[2]), xl2); pkfma(d0v, hi2(qw0[2]), xh2);
      pkfma(d0v, lo2(qw0[3]), xl3); pkfma(d0v, hi2(qw0[3]), xh3);
      pkfma(d1v, lo2(qw1[0]), xl0); pkfma(d1v, hi2(qw1[0]), xh0);
      pkfma(d1v, lo2(qw1[1]), xl1); pkfma(d1v, hi2(qw1[1]), xh1);
      pkfma(d1v, lo2(qw1[2]), xl2); pkfma(d1v, hi2(qw1[2]), xh2);
      pkfma(d1v, lo2(qw1[3]), xl3); pkfma(d1v, hi2(qw1[3]), xh3);
      float D0 = rsum_u(d0v.x + d0v.y);
      float D1 = rsum_u(d1v.x + d1v.y);
      float2 mr = *(const float2*)mr_lds[cur][r];  // broadcast read
      float mu = mr.x, rs = mr.y;
      float l0 = fminf(rs * (D0 - mu * qs0) + qb0, 75.f);  // logits tiny; clamp = inf guard
      float l1 = fminf(rs * (D1 - mu * qs1) + qb1, 75.f);
      float p0 = __expf(l0), p1 = __expf(l1);
      float w0 = p0 * rs, w1 = p1 * rs;
      e0 += p0; e1 += p1;
      un0 += w0 * mu; un1 += w1 * mu;
      v2f w0v = v2f{w0, w0}, w1v = v2f{w1, w1};
      pkfma(acc0[0], w0v, xl0); pkfma(acc0[1], w0v, xh0);
      pkfma(acc0[2], w0v, xl1); pkfma(acc0[3], w0v, xh1);
      pkfma(acc0[4], w0v, xl2); pkfma(acc0[5], w0v, xh2);
      pkfma(acc0[6], w0v, xl3); pkfma(acc0[7], w0v, xh3);
      pkfma(acc1[0], w1v, xl0); pkfma(acc1[1], w1v, xh0);
      pkfma(acc1[2], w1v, xl1); pkfma(acc1[3], w1v, xh1);
      pkfma(acc1[4], w1v, xl2); pkfma(acc1[5], w1v, xh2);
      pkfma(acc1[6], w1v, xl3); pkfma(acc1[7], w1v, xh3);
    }
  }

  // ---- store partials (m == 0 by construction; logits bounded ~|2|)
  float4* p0 = (float4*)(part_s + ((size_t)bc * HH + h0) * CC);
  float4* p1 = (float4*)(part_s + ((size_t)bc * HH + h0 + 1) * CC);
#pragma unroll
  for (int k = 0; k < 4; ++k) {
    p0[64 * k + lane] = make_float4(acc0[2 * k].x, acc0[2 * k].y,
                                    acc0[2 * k + 1].x, acc0[2 * k + 1].y);
    p1[64 * k + lane] = make_float4(acc1[2 * k].x, acc1[2 * k].y,
                                    acc1[2 * k + 1].x, acc1[2 * k + 1].y);
  }
  if (lane == 0) {
    float* pm = part_meu + ((size_t)bc * HH + h0) * 2;
    pm[0] = e0; pm[1] = un0;
    pm[2] = e1; pm[3] = un1;
  }
}

// ---- merge partials: s[b,h,c] = gamma*(S-UN)/E + beta ----
__global__ __launch_bounds__(256) void kmerge(
    const float* __restrict__ part_s, const float* __restrict__ part_meu,
    const float* __restrict__ kvg, const float* __restrict__ kvb,
    float* __restrict__ s) {
  int h = blockIdx.x >> 2, q = blockIdx.x & 3, b = blockIdx.y;
  int col = q * 256 + threadIdx.x;
  float E = 0.f, UN = 0.f, a = 0.f;
  for (int ch = 0; ch < CHUNKS; ++ch) {
    const float* pm = part_meu + (((size_t)b * CHUNKS + ch) * HH + h) * 2;
    E += pm[0];
    UN += pm[1];
    a += part_s[(((size_t)b * CHUNKS + ch) * HH + h) * CC + col];
  }
  float inv = 1.f / E;
  s[((size_t)b * HH + h) * CC + col] = kvg[col] * (a - UN) * inv + kvb[col];
}

// ---- k5: agg[b,j] = Wkv[C+j,:] . s[b, j/D, :] ----
__global__ __launch_bounds__(256) void k5(const float* __restrict__ Wkv,
                                          const float* __restrict__ s,
                                          float* __restrict__ agg) {
  int lane = threadIdx.x & 63;
  int j = blockIdx.x * 4 + (threadIdx.x >> 6);
  int h = j >> 7;
  const float4* wr = (const float4*)(Wkv + ((size_t)(CC + j)) * CC);
  float4 wv[4];
#pragma unroll
  for (int k = 0; k < 4; ++k) wv[k] = wr[lane + 64 * k];
  for (int b = 0; b < BB; ++b) {
    const float4* s4 = (const float4*)(s + ((size_t)(b * HH + h)) * CC);
    float a = 0.f;
#pragma unroll
    for (int k = 0; k < 4; ++k) a += dot4(wv[k], s4[lane + 64 * k]);
    a = wsum(a);
    if (lane == 0) agg[b * CC + j] = a;
  }
}

// ---- k6: out[b,j] = cf[j] + agg[b,:] . proj_W[j,:] + proj_b[j] ----
__global__ __launch_bounds__(256) void k6(const float* __restrict__ pW,
                                          const float* __restrict__ agg,
                                          const float* __restrict__ cf,
                                          const float* __restrict__ pb,
                                          float* __restrict__ out) {
  int lane = threadIdx.x & 63;
  int j = blockIdx.x * 4 + (threadIdx.x >> 6);
  const float4* wr = (const float4*)(pW + (size_t)j * CC);
  float4 wv[4];
#pragma unroll
  for (int k = 0; k < 4; ++k) wv[k] = wr[lane + 64 * k];
  for (int b = 0; b < BB; ++b) {
    const float4* a4 = (const float4*)(agg + (size_t)b * CC);
    float a = 0.f;
#pragma unroll
    for (int k = 0; k < 4; ++k) a += dot4(wv[k], a4[lane + 64 * k]);
    a = wsum(a);
    if (lane == 0) out[b * CC + j] = cf[j] + a + pb[j];
  }
}

// ws float offsets
constexpr size_t WS_QVEC = 0;        // 1024
constexpr size_t WS_QW   = 1024;     // 8192
constexpr size_t WS_QWG  = 9216;     // 8192
constexpr size_t WS_S    = 17408;    // 131072
constexpr size_t WS_AGG  = 148480;   // 16384
constexpr size_t WS_PMEU = 164864;   // 8192
constexpr size_t WS_PART = 173056;   // 4194304 (16.8 MB)

extern "C" void kernel_launch(void* const* d_in, const int* in_sizes, int n_in,
                              void* d_out, int out_size, void* d_ws, size_t ws_size,
                              hipStream_t stream) {
  const float* cf = (const float*)d_in[0];
  const float* x = (const float*)d_in[1];
  const float* qg = (const float*)d_in[2];
  const float* qb = (const float*)d_in[3];
  const float* Wq = (const float*)d_in[4];
  const float* kvg = (const float*)d_in[5];
  const float* kvb = (const float*)d_in[6];
  const float* Wkv = (const float*)d_in[7];
  const float* pW = (const float*)d_in[8];
  const float* pb = (const float*)d_in[9];
  float* ws = (float*)d_ws;
  float* out = (float*)d_out;

  k0b<<<256, 256, 0, stream>>>(cf, qg, qb, Wq, ws + WS_QVEC);
  k0c<<<128, 256, 0, stream>>>(ws + WS_QVEC, Wkv, kvg, ws + WS_QW, ws + WS_QWG);
  kfused<<<dim3(CHUNKS, BB), 256, 0, stream>>>(x, ws + WS_QWG, ws + WS_QW, kvb,
                                               ws + WS_PART, ws + WS_PMEU);
  kmerge<<<dim3(HH * 4, BB), 256, 0, stream>>>(ws + WS_PART, ws + WS_PMEU, kvg, kvb,
                                               ws + WS_S);
  k5<<<256, 256, 0, stream>>>(Wkv, ws + WS_S, ws + WS_AGG);
  k6<<<256, 256, 0, stream>>>(pW, ws + WS_AGG, cf, pb, out);
}